// Round 4
// baseline (219.733 us; speedup 1.0000x reference)
//
#include <hip/hip_runtime.h>
#include <hip/hip_bf16.h>
#include <float.h>

#define N_NODES 100000
#define HID     512
#define NGRAPH  1024
#define BM      48            // rows per block
#define NBLK    ((N_NODES + BM - 1) / BM)   // 2084

typedef __bf16 bf16_t;
typedef bf16_t bf16x4 __attribute__((ext_vector_type(4)));
typedef bf16_t bf16x8 __attribute__((ext_vector_type(8)));
typedef float  f32x4  __attribute__((ext_vector_type(4)));

// global -> LDS direct DMA, 16B per lane; LDS dest is wave-uniform base + lane*16.
#define GLOAD_LDS16(g, l)                                                        \
    __builtin_amdgcn_global_load_lds(                                            \
        (const __attribute__((address_space(1))) unsigned int*)(g),              \
        (__attribute__((address_space(3))) unsigned int*)(l), 16, 0, 0)

// ---- Kernel 0: W1 [K][N] f32 -> tiled bf16 B: unit u=(kt*4+g)*512+col holds
// bf16x8 = W1[kt*32+g*8+e][col], e=0..7.  (16 kt) x (4 g) x (512 col) ----------
__global__ void __launch_bounds__(256) k_w1t_tiled(const float* __restrict__ w1,
                                                   bf16_t* __restrict__ bt) {
    const int u   = blockIdx.x * 256 + threadIdx.x;   // 0 .. 32767
    const int col = u & 511;
    const int g4  = u >> 9;          // kt*4 + g  (0..63)
    const int k0  = g4 * 8;          // kt*32 + g*8
    bf16x8 v;
    #pragma unroll
    for (int e = 0; e < 8; ++e)
        v[e] = (bf16_t)w1[(size_t)(k0 + e) * HID + col];
    *reinterpret_cast<bf16x8*>(bt + (size_t)u * 8) = v;
}

// ---- Kernel 1: fused GEMM + gelu + dot(W2) -> gate --------------------------
// Block: 48 rows x 512 cols x 512 K. A resident (48KB, swizzled), B streamed in
// 16 K-tiles of 32 (32KB, tiled layout, conflict-free). 512 thr = 8 waves, each
// wave owns 64 cols x all 48 rows: acc[3][4].
// launch_bounds(512,2): 256-reg budget -> NO SPILLS (512,4 split 64+64 and spilled
// ~100MB of scratch traffic in round 3).
__global__ void __launch_bounds__(512, 2) k_gemm_gate(const float* __restrict__ h,
                                                      const bf16_t* __restrict__ bt,
                                                      const float* __restrict__ b1,
                                                      const float* __restrict__ w2,
                                                      const float* __restrict__ b2,
                                                      float* __restrict__ gate) {
    __shared__ __align__(16) char smem[BM * 1024 + 32768];   // 48KB A + 32KB B = 80KB
    bf16_t* As = (bf16_t*)smem;                   // [48 rows][512 k], 1KB rows, swizzled
    char*   Bs = smem + BM * 1024;                // [4 g][512 col] 16B units per K-tile

    const int tid  = threadIdx.x;
    const int lane = tid & 63;
    const int wv   = tid >> 6;     // 0..7 : wave owns cols [wv*64, wv*64+64)
    const int l15  = lane & 15;
    const int l4   = lane >> 4;    // 0..3

    const int brow = blockIdx.x * BM;

    // ================= stage A: 48 rows x 2KB, fully coalesced =================
    // unit idx = i*512 + tid : row = idx>>7, c16 = idx&127 (16B f32 chunk)
    f32x4 st[12];
    #pragma unroll
    for (int i = 0; i < 12; ++i) {
        const int idx = i * 512 + tid;
        const int row = idx >> 7;
        const int c16 = idx & 127;
        const int grow = brow + row;
        if (grow < N_NODES)
            st[i] = *reinterpret_cast<const f32x4*>(h + (size_t)grow * HID + c16 * 4);
        else
            st[i] = f32x4{0.f, 0.f, 0.f, 0.f};
    }
    // stage B tile 0 (DMA) while A loads are in flight
    {
        const char* src = (const char*)bt + (size_t)wv * 1024 + lane * 16;
        #pragma unroll
        for (int r = 0; r < 4; ++r)
            GLOAD_LDS16(src + r * 8192, Bs + r * 8192 + wv * 1024);
    }
    // cvt + swizzled LDS write of A (8B per unit)
    #pragma unroll
    for (int i = 0; i < 12; ++i) {
        const int idx = i * 512 + tid;
        const int row = idx >> 7;
        const int c16 = idx & 127;
        const int chunk = c16 >> 1;                    // 16B bf16 chunk (k-span 8)
        const int half  = c16 & 1;
        bf16x4 t;
        t[0] = (bf16_t)st[i][0]; t[1] = (bf16_t)st[i][1];
        t[2] = (bf16_t)st[i][2]; t[3] = (bf16_t)st[i][3];
        *reinterpret_cast<bf16x4*>(
            (char*)As + row * 1024 + ((chunk ^ (row & 7)) * 16) + half * 8) = t;
    }
    __syncthreads();   // A in LDS + B[0] DMA drained

    // ================= K loop: 16 tiles of 32 ==================================
    f32x4 acc[3][4] = {};
    for (int kt = 0; kt < 16; ++kt) {
        // fragment loads from LDS
        bf16x8 af[3], bfr[4];
        #pragma unroll
        for (int mf = 0; mf < 3; ++mf) {
            const int row   = mf * 16 + l15;
            const int chunk = (kt * 4 + l4) ^ (row & 7);
            af[mf] = *reinterpret_cast<const bf16x8*>(
                (const char*)As + row * 1024 + chunk * 16);
        }
        #pragma unroll
        for (int nf = 0; nf < 4; ++nf) {
            const int col = wv * 64 + nf * 16 + l15;
            bfr[nf] = *reinterpret_cast<const bf16x8*>(
                Bs + (l4 * 512 + col) * 16);
        }
        __syncthreads();   // all frags read -> Bs reusable
        // issue next B tile DMA (lands under the MFMAs)
        if (kt < 15) {
            const char* src = (const char*)bt + (size_t)(kt + 1) * 32768
                              + (size_t)wv * 1024 + lane * 16;
            #pragma unroll
            for (int r = 0; r < 4; ++r)
                GLOAD_LDS16(src + r * 8192, Bs + r * 8192 + wv * 1024);
        }
        #pragma unroll
        for (int mf = 0; mf < 3; ++mf)
            #pragma unroll
            for (int nf = 0; nf < 4; ++nf)
                acc[mf][nf] = __builtin_amdgcn_mfma_f32_16x16x32_bf16(
                    af[mf], bfr[nf], acc[mf][nf], 0, 0, 0);
        __syncthreads();   // next B tile arrived (barrier drains vmcnt)
    }

    // ================= epilogue: gelu(acc+b1)*w2, reduce 512 cols ==============
    float pr[12];
    #pragma unroll
    for (int i = 0; i < 12; ++i) pr[i] = 0.f;
    #pragma unroll
    for (int nf = 0; nf < 4; ++nf) {
        const int cg    = wv * 64 + nf * 16 + l15;
        const float b1v = b1[cg];
        const float w2v = w2[cg];
        #pragma unroll
        for (int mf = 0; mf < 3; ++mf) {
            #pragma unroll
            for (int rr = 0; rr < 4; ++rr) {
                const float x  = acc[mf][nf][rr] + b1v;
                const float ge = 0.5f * x * (1.f + erff(x * 0.70710678118654752f));
                pr[mf * 4 + rr] = fmaf(ge, w2v, pr[mf * 4 + rr]);
            }
        }
    }
    #pragma unroll
    for (int i = 0; i < 12; ++i) {
        float v = pr[i];
        v += __shfl_xor(v, 1);
        v += __shfl_xor(v, 2);
        v += __shfl_xor(v, 4);
        v += __shfl_xor(v, 8);
        pr[i] = v;
    }
    // overlay per-wave row partials on Bs (all Bs reads are done)
    float* gp = (float*)Bs;      // [8 waves][48 rows]
    if (l15 == 0) {
        #pragma unroll
        for (int mf = 0; mf < 3; ++mf)
            #pragma unroll
            for (int rr = 0; rr < 4; ++rr)
                gp[wv * BM + mf * 16 + l4 * 4 + rr] = pr[mf * 4 + rr];
    }
    __syncthreads();
    if (tid < BM) {
        const int grow = brow + tid;
        if (grow < N_NODES) {
            float s = b2[0];
            #pragma unroll
            for (int w = 0; w < 8; ++w) s += gp[w * BM + tid];
            gate[grow] = s;
        }
    }
}

// ---- Kernel 2: segment softmax + weighted pool ------------------------------
__global__ void __launch_bounds__(256) k_pool(const float* __restrict__ h,
                                              const int* __restrict__ bv,
                                              const float* __restrict__ gate,
                                              float* __restrict__ out) {
    const int g   = blockIdx.x;
    const int tid = threadIdx.x;
    __shared__ int   s_bounds[2];
    __shared__ float s_red[4];
    __shared__ float s_alpha[256];

    if (tid == 0) {
        int lo = 0, hi = N_NODES;
        while (lo < hi) { int mid = (lo + hi) >> 1; if (bv[mid] < g) lo = mid + 1; else hi = mid; }
        s_bounds[0] = lo;
        int lo2 = lo, hi2 = N_NODES;
        while (lo2 < hi2) { int mid = (lo2 + hi2) >> 1; if (bv[mid] < g + 1) lo2 = mid + 1; else hi2 = mid; }
        s_bounds[1] = lo2;
    }
    __syncthreads();
    const int start = s_bounds[0], end = s_bounds[1];

    float2 acc = make_float2(0.f, 0.f);
    if (start < end) {
        const int lane = tid & 63, wv = tid >> 6;
        float lm = -FLT_MAX;
        for (int i = start + tid; i < end; i += 256) lm = fmaxf(lm, gate[i]);
        #pragma unroll
        for (int o = 32; o; o >>= 1) lm = fmaxf(lm, __shfl_xor(lm, o));
        if (lane == 0) s_red[wv] = lm;
        __syncthreads();
        const float m = fmaxf(fmaxf(s_red[0], s_red[1]), fmaxf(s_red[2], s_red[3]));
        __syncthreads();
        float ls = 0.f;
        for (int i = start + tid; i < end; i += 256) ls += expf(gate[i] - m);
        #pragma unroll
        for (int o = 32; o; o >>= 1) ls += __shfl_xor(ls, o);
        if (lane == 0) s_red[wv] = ls;
        __syncthreads();
        const float inv = 1.f / (s_red[0] + s_red[1] + s_red[2] + s_red[3]);
        const float* hcol = h + tid * 2;
        for (int base = start; base < end; base += 256) {
            const int j = base + tid;
            const float av = (j < end) ? expf(gate[j] - m) * inv : 0.f;
            __syncthreads();
            s_alpha[tid] = av;
            __syncthreads();
            const int cnt = min(256, end - base);
            for (int jj = 0; jj < cnt; ++jj) {
                const float a = s_alpha[jj];
                const float2 hv = *reinterpret_cast<const float2*>(
                    hcol + (size_t)(base + jj) * HID);
                acc.x = fmaf(a, hv.x, acc.x);
                acc.y = fmaf(a, hv.y, acc.y);
            }
        }
    }
    *reinterpret_cast<float2*>(out + (size_t)g * HID + tid * 2) = acc;
}

// ---- launcher ---------------------------------------------------------------
extern "C" void kernel_launch(void* const* d_in, const int* in_sizes, int n_in,
                              void* d_out, int out_size, void* d_ws, size_t ws_size,
                              hipStream_t stream) {
    const float* h  = (const float*)d_in[0];
    const int*   bv = (const int*)d_in[1];
    const float* W1 = (const float*)d_in[2];
    const float* b1 = (const float*)d_in[3];
    const float* W2 = (const float*)d_in[4];
    const float* b2 = (const float*)d_in[5];
    float* out = (float*)d_out;

    char* ws = (char*)d_ws;
    bf16_t* bt   = (bf16_t*)ws;                    // tiled B: 512*512*2 = 524288 B
    float*  gate = (float*)(ws + 524288);          // 100000*4 B

    k_w1t_tiled<<<dim3(128), dim3(256), 0, stream>>>(W1, bt);
    k_gemm_gate<<<dim3(NBLK), dim3(512), 0, stream>>>(h, bt, b1, W2, b2, gate);
    k_pool<<<dim3(NGRAPH), dim3(256), 0, stream>>>(h, bv, gate, out);
}

// Round 5
// 181.070 us; speedup vs baseline: 1.2135x; 1.2135x over previous
//
#include <hip/hip_runtime.h>
#include <hip/hip_bf16.h>
#include <float.h>

#define N_NODES 100000
#define HID     512
#define NGRAPH  1024
#define BM      48            // rows per block
#define NBLK    ((N_NODES + BM - 1) / BM)   // 2084

typedef __bf16 bf16_t;
typedef bf16_t bf16x8 __attribute__((ext_vector_type(8)));
typedef float  f32x4  __attribute__((ext_vector_type(4)));

// ---- Kernel 0: W1 [K][N] f32 -> tiled bf16 B: unit u=(kt*4+g)*512+col holds
// bf16x8 = W1[kt*32+g*8+e][col], e=0..7.  (16 kt) x (4 g) x (512 col) ----------
__global__ void __launch_bounds__(256) k_w1t_tiled(const float* __restrict__ w1,
                                                   bf16_t* __restrict__ bt) {
    const int u   = blockIdx.x * 256 + threadIdx.x;   // 0 .. 32767
    const int col = u & 511;
    const int g4  = u >> 9;          // kt*4 + g  (0..63)
    const int k0  = g4 * 8;          // kt*32 + g*8
    bf16x8 v;
    #pragma unroll
    for (int e = 0; e < 8; ++e)
        v[e] = (bf16_t)w1[(size_t)(k0 + e) * HID + col];
    *reinterpret_cast<bf16x8*>(bt + (size_t)u * 8) = v;
}

// ---- Kernel 1: fused GEMM + gelu + dot(W2) -> gate --------------------------
// Block: 48 rows x 512 cols x 512 K. A resident in LDS (48KB, swizzled, staged
// once). B: DIRECT global->reg loads from L2-resident tiled bt, double-buffered
// in registers, K-loop fully unrolled -> ZERO barriers / ZERO LDS writes / ZERO
// vmcnt(0) drains in the loop. 512 thr = 8 waves; wave owns 64 cols x 48 rows.
__global__ void __launch_bounds__(512, 2) k_gemm_gate(const float* __restrict__ h,
                                                      const bf16_t* __restrict__ bt,
                                                      const float* __restrict__ b1,
                                                      const float* __restrict__ w2,
                                                      const float* __restrict__ b2,
                                                      float* __restrict__ gate) {
    __shared__ __align__(16) bf16_t As[BM * HID];   // 48KB: [48 rows][512 k], swizzled
    __shared__ float gp[8][BM];                     // per-wave row partials (1.5KB)

    const int tid  = threadIdx.x;
    const int lane = tid & 63;
    const int wv   = tid >> 6;     // 0..7 : wave owns cols [wv*64, wv*64+64)
    const int l15  = lane & 15;
    const int l4   = lane >> 4;    // 0..3

    const int brow = blockIdx.x * BM;

    // ================= stage A: 48 rows x 2KB, coalesced, b128 LDS writes ======
    // 32B-f32 unit: idx = i*512 + tid ; row = idx>>6, cu = idx&63 (16B bf16 chunk)
    f32x4 st[12];
    #pragma unroll
    for (int i = 0; i < 6; ++i) {
        const int idx = i * 512 + tid;
        const int row = idx >> 6;
        const int cu  = idx & 63;
        const int grow = brow + row;
        if (grow < N_NODES) {
            const f32x4* p = reinterpret_cast<const f32x4*>(
                h + (size_t)grow * HID + cu * 8);
            st[2 * i]     = p[0];
            st[2 * i + 1] = p[1];
        } else {
            st[2 * i] = f32x4{0.f, 0.f, 0.f, 0.f};
            st[2 * i + 1] = f32x4{0.f, 0.f, 0.f, 0.f};
        }
    }

    // ---- B fragment geometry: direct global loads from tiled bt ----
    // unit for (kt, nf): (kt*4 + l4)*512 + wv*64 + nf*16 + l15 ; 8 elems/unit
    const bf16_t* bbase = bt + ((size_t)l4 * 512 + wv * 64 + l15) * 8;
    bf16x8 breg[2][4];
    #pragma unroll
    for (int nf = 0; nf < 4; ++nf)     // tile 0 (overlaps A staging latency)
        breg[0][nf] = *reinterpret_cast<const bf16x8*>(bbase + nf * 128);

    // ---- cvt + swizzled b128 LDS write of A (conflict-free: 2-way) ----
    #pragma unroll
    for (int i = 0; i < 6; ++i) {
        const int idx = i * 512 + tid;
        const int row = idx >> 6;
        const int cu  = idx & 63;
        bf16x8 v;
        #pragma unroll
        for (int j = 0; j < 4; ++j) { v[j] = (bf16_t)st[2*i][j]; v[4+j] = (bf16_t)st[2*i+1][j]; }
        *reinterpret_cast<bf16x8*>(
            (char*)As + row * 1024 + ((cu ^ (row & 7)) * 16)) = v;
    }
    __syncthreads();   // the ONLY barrier before the epilogue

    // ================= K loop: 16 tiles of 32, fully unrolled, barrier-free ====
    const char* abase = (const char*)As + l15 * 1024;   // + mf*16384 + chunkoff
    f32x4 acc[3][4] = {};
    #pragma unroll
    for (int kt = 0; kt < 16; ++kt) {
        if (kt < 15) {   // prefetch next B tile into the other reg buffer
            #pragma unroll
            for (int nf = 0; nf < 4; ++nf)
                breg[(kt + 1) & 1][nf] = *reinterpret_cast<const bf16x8*>(
                    bbase + (size_t)(kt + 1) * 16384 + nf * 128);
        }
        const int chunkoff = (((kt * 4) + l4) ^ (l15 & 7)) * 16;
        bf16x8 af[3];
        #pragma unroll
        for (int mf = 0; mf < 3; ++mf)
            af[mf] = *reinterpret_cast<const bf16x8*>(abase + mf * 16384 + chunkoff);
        #pragma unroll
        for (int mf = 0; mf < 3; ++mf)
            #pragma unroll
            for (int nf = 0; nf < 4; ++nf)
                acc[mf][nf] = __builtin_amdgcn_mfma_f32_16x16x32_bf16(
                    af[mf], breg[kt & 1][nf], acc[mf][nf], 0, 0, 0);
    }

    // ================= epilogue: gelu(acc+b1)*w2, reduce 512 cols ==============
    float pr[12];
    #pragma unroll
    for (int i = 0; i < 12; ++i) pr[i] = 0.f;
    #pragma unroll
    for (int nf = 0; nf < 4; ++nf) {
        const int cg    = wv * 64 + nf * 16 + l15;
        const float b1v = b1[cg];
        const float w2v = w2[cg];
        #pragma unroll
        for (int mf = 0; mf < 3; ++mf) {
            #pragma unroll
            for (int rr = 0; rr < 4; ++rr) {
                const float x  = acc[mf][nf][rr] + b1v;
                const float ge = 0.5f * x * (1.f + erff(x * 0.70710678118654752f));
                pr[mf * 4 + rr] = fmaf(ge, w2v, pr[mf * 4 + rr]);
            }
        }
    }
    #pragma unroll
    for (int i = 0; i < 12; ++i) {
        float v = pr[i];
        v += __shfl_xor(v, 1);
        v += __shfl_xor(v, 2);
        v += __shfl_xor(v, 4);
        v += __shfl_xor(v, 8);
        pr[i] = v;
    }
    if (l15 == 0) {
        #pragma unroll
        for (int mf = 0; mf < 3; ++mf)
            #pragma unroll
            for (int rr = 0; rr < 4; ++rr)
                gp[wv][mf * 16 + l4 * 4 + rr] = pr[mf * 4 + rr];
    }
    __syncthreads();
    if (tid < BM) {
        const int grow = brow + tid;
        if (grow < N_NODES) {
            float s = b2[0];
            #pragma unroll
            for (int w = 0; w < 8; ++w) s += gp[w][tid];
            gate[grow] = s;
        }
    }
}

// ---- Kernel 2: segment softmax + weighted pool ------------------------------
__global__ void __launch_bounds__(256) k_pool(const float* __restrict__ h,
                                              const int* __restrict__ bv,
                                              const float* __restrict__ gate,
                                              float* __restrict__ out) {
    const int g   = blockIdx.x;
    const int tid = threadIdx.x;
    __shared__ int   s_bounds[2];
    __shared__ float s_red[4];
    __shared__ float s_alpha[256];

    if (tid == 0) {
        int lo = 0, hi = N_NODES;
        while (lo < hi) { int mid = (lo + hi) >> 1; if (bv[mid] < g) lo = mid + 1; else hi = mid; }
        s_bounds[0] = lo;
        int lo2 = lo, hi2 = N_NODES;
        while (lo2 < hi2) { int mid = (lo2 + hi2) >> 1; if (bv[mid] < g + 1) lo2 = mid + 1; else hi2 = mid; }
        s_bounds[1] = lo2;
    }
    __syncthreads();
    const int start = s_bounds[0], end = s_bounds[1];

    float2 acc = make_float2(0.f, 0.f);
    if (start < end) {
        const int lane = tid & 63, wv = tid >> 6;
        float lm = -FLT_MAX;
        for (int i = start + tid; i < end; i += 256) lm = fmaxf(lm, gate[i]);
        #pragma unroll
        for (int o = 32; o; o >>= 1) lm = fmaxf(lm, __shfl_xor(lm, o));
        if (lane == 0) s_red[wv] = lm;
        __syncthreads();
        const float m = fmaxf(fmaxf(s_red[0], s_red[1]), fmaxf(s_red[2], s_red[3]));
        __syncthreads();
        float ls = 0.f;
        for (int i = start + tid; i < end; i += 256) ls += expf(gate[i] - m);
        #pragma unroll
        for (int o = 32; o; o >>= 1) ls += __shfl_xor(ls, o);
        if (lane == 0) s_red[wv] = ls;
        __syncthreads();
        const float inv = 1.f / (s_red[0] + s_red[1] + s_red[2] + s_red[3]);
        const float* hcol = h + tid * 2;
        for (int base = start; base < end; base += 256) {
            const int j = base + tid;
            const float av = (j < end) ? expf(gate[j] - m) * inv : 0.f;
            __syncthreads();
            s_alpha[tid] = av;
            __syncthreads();
            const int cnt = min(256, end - base);
            for (int jj = 0; jj < cnt; ++jj) {
                const float a = s_alpha[jj];
                const float2 hv = *reinterpret_cast<const float2*>(
                    hcol + (size_t)(base + jj) * HID);
                acc.x = fmaf(a, hv.x, acc.x);
                acc.y = fmaf(a, hv.y, acc.y);
            }
        }
    }
    *reinterpret_cast<float2*>(out + (size_t)g * HID + tid * 2) = acc;
}

// ---- launcher ---------------------------------------------------------------
extern "C" void kernel_launch(void* const* d_in, const int* in_sizes, int n_in,
                              void* d_out, int out_size, void* d_ws, size_t ws_size,
                              hipStream_t stream) {
    const float* h  = (const float*)d_in[0];
    const int*   bv = (const int*)d_in[1];
    const float* W1 = (const float*)d_in[2];
    const float* b1 = (const float*)d_in[3];
    const float* W2 = (const float*)d_in[4];
    const float* b2 = (const float*)d_in[5];
    float* out = (float*)d_out;

    char* ws = (char*)d_ws;
    bf16_t* bt   = (bf16_t*)ws;                    // tiled B: 512*512*2 = 524288 B
    float*  gate = (float*)(ws + 524288);          // 100000*4 B

    k_w1t_tiled<<<dim3(128), dim3(256), 0, stream>>>(W1, bt);
    k_gemm_gate<<<dim3(NBLK), dim3(512), 0, stream>>>(h, bt, b1, W2, b2, gate);
    k_pool<<<dim3(NGRAPH), dim3(256), 0, stream>>>(h, bv, gate, out);
}

// Round 7
// 158.385 us; speedup vs baseline: 1.3873x; 1.1432x over previous
//
#include <hip/hip_runtime.h>
#include <hip/hip_bf16.h>
#include <float.h>

#define N_NODES 100000
#define HID     512
#define NGRAPH  1024
#define BM      48            // rows per block
#define NBLK    ((N_NODES + BM - 1) / BM)   // 2084

typedef __bf16 bf16_t;
typedef bf16_t bf16x8 __attribute__((ext_vector_type(8)));
typedef float  f32x4  __attribute__((ext_vector_type(4)));

// Branch-free gelu: erf via Abramowitz-Stegun 7.1.26 (|err|<=1.5e-7), exact-form
// gelu(x) = 0.5 x (1 + erf(x/sqrt2)). ~14 VALU instrs vs ~80 for ocml erff.
__device__ __forceinline__ float fast_gelu(float x) {
    const float z = __builtin_fabsf(x) * 0.70710678118654752f;
    const float t = __fdividef(1.0f, __builtin_fmaf(0.3275911f, z, 1.0f));
    float p = __builtin_fmaf(1.061405429f, t, -1.453152027f);
    p = __builtin_fmaf(p, t, 1.421413741f);
    p = __builtin_fmaf(p, t, -0.284496736f);
    p = __builtin_fmaf(p, t, 0.254829592f);
    p *= t;
    const float e    = __expf(-z * z);
    const float erfz = __builtin_fmaf(-p, e, 1.0f);      // erf(|z|) >= 0
    const float s    = __builtin_copysignf(erfz, x);
    return 0.5f * x * (1.0f + s);
}

// ---- Kernel 0: W1 [K][N] f32 -> tiled bf16 B: unit u=(kt*4+g)*512+col holds
// bf16x8 = W1[kt*32+g*8+e][col], e=0..7.  (16 kt) x (4 g) x (512 col) ----------
__global__ void __launch_bounds__(256) k_w1t_tiled(const float* __restrict__ w1,
                                                   bf16_t* __restrict__ bt) {
    const int u   = blockIdx.x * 256 + threadIdx.x;   // 0 .. 32767
    const int col = u & 511;
    const int g4  = u >> 9;          // kt*4 + g  (0..63)
    const int k0  = g4 * 8;          // kt*32 + g*8
    bf16x8 v;
    #pragma unroll
    for (int e = 0; e < 8; ++e)
        v[e] = (bf16_t)w1[(size_t)(k0 + e) * HID + col];
    *reinterpret_cast<bf16x8*>(bt + (size_t)u * 8) = v;
}

// ---- Kernel 1: fused GEMM + gelu + dot(W2) -> gate --------------------------
// Block: 48 rows x 512 cols x 512 K. A resident in LDS (48KB, swizzled, staged
// once). B: direct global->reg from L2-resident tiled bt, DISTANCE-2 prefetch
// (covers ~300cy L2 latency); A-frags ds_read one iter ahead. Zero barriers in
// the K-loop. 512 thr = 8 waves; wave owns 64 cols x 48 rows (acc[3][4]).
__global__ void __launch_bounds__(512, 2) k_gemm_gate(const float* __restrict__ h,
                                                      const bf16_t* __restrict__ bt,
                                                      const float* __restrict__ b1,
                                                      const float* __restrict__ w2,
                                                      const float* __restrict__ b2,
                                                      float* __restrict__ gate) {
    __shared__ __align__(16) bf16_t As[BM * HID];   // 48KB: [48 rows][512 k], swizzled
    __shared__ float gp[8][BM];                     // per-wave row partials (1.5KB)

    const int tid  = threadIdx.x;
    const int lane = tid & 63;
    const int wv   = tid >> 6;     // 0..7 : wave owns cols [wv*64, wv*64+64)
    const int l15  = lane & 15;
    const int l4   = lane >> 4;    // 0..3

    const int brow = blockIdx.x * BM;

    // ================= stage A: 48 rows x 2KB, coalesced =======================
    f32x4 st[12];
    #pragma unroll
    for (int i = 0; i < 6; ++i) {
        const int idx = i * 512 + tid;
        const int row = idx >> 6;
        const int cu  = idx & 63;
        const int grow = brow + row;
        if (grow < N_NODES) {
            const f32x4* p = reinterpret_cast<const f32x4*>(
                h + (size_t)grow * HID + cu * 8);
            st[2 * i]     = p[0];
            st[2 * i + 1] = p[1];
        } else {
            st[2 * i] = f32x4{0.f, 0.f, 0.f, 0.f};
            st[2 * i + 1] = f32x4{0.f, 0.f, 0.f, 0.f};
        }
    }

    // ---- B fragment geometry: direct global loads from tiled bt ----
    // unit for (kt, nf): (kt*4 + l4)*512 + wv*64 + nf*16 + l15 ; 8 elems/unit
    // => address = bbase + kt*16384 + nf*128 (in bf16 elements)
    const bf16_t* bbase = bt + ((size_t)l4 * 512 + wv * 64 + l15) * 8;
    bf16x8 breg[2][4];
    #pragma unroll
    for (int nf = 0; nf < 4; ++nf)     // tile 0 (overlaps A staging latency)
        breg[0][nf] = *reinterpret_cast<const bf16x8*>(bbase + nf * 128);
    #pragma unroll
    for (int nf = 0; nf < 4; ++nf)     // tile 1
        breg[1][nf] = *reinterpret_cast<const bf16x8*>(bbase + 16384 + nf * 128);

    // ---- cvt + swizzled b128 LDS write of A (2-way, conflict-light) ----
    #pragma unroll
    for (int i = 0; i < 6; ++i) {
        const int idx = i * 512 + tid;
        const int row = idx >> 6;
        const int cu  = idx & 63;
        bf16x8 v;
        #pragma unroll
        for (int j = 0; j < 4; ++j) { v[j] = (bf16_t)st[2*i][j]; v[4+j] = (bf16_t)st[2*i+1][j]; }
        *reinterpret_cast<bf16x8*>(
            (char*)As + row * 1024 + ((cu ^ (row & 7)) * 16)) = v;
    }
    __syncthreads();   // the ONLY barrier before the epilogue

    // ================= K loop: 16 tiles of 32, unrolled, barrier-free ==========
    const char* abase = (const char*)As + l15 * 1024;   // + mf*16384 + chunkoff
    f32x4 acc[3][4] = {};
    bf16x8 af[2][3];
    {   // A frags for tile 0
        const int chunkoff = ((0 + l4) ^ (l15 & 7)) * 16;
        #pragma unroll
        for (int mf = 0; mf < 3; ++mf)
            af[0][mf] = *reinterpret_cast<const bf16x8*>(abase + mf * 16384 + chunkoff);
    }
    #pragma unroll
    for (int kt = 0; kt < 16; ++kt) {
        // A frags for kt+1 (ds_read latency hides under this iter's MFMAs)
        if (kt < 15) {
            const int chunkoff = (((kt + 1) * 4 + l4) ^ (l15 & 7)) * 16;
            #pragma unroll
            for (int mf = 0; mf < 3; ++mf)
                af[(kt + 1) & 1][mf] = *reinterpret_cast<const bf16x8*>(
                    abase + mf * 16384 + chunkoff);
        }
        #pragma unroll
        for (int mf = 0; mf < 3; ++mf)
            #pragma unroll
            for (int nf = 0; nf < 4; ++nf)
                acc[mf][nf] = __builtin_amdgcn_mfma_f32_16x16x32_bf16(
                    af[kt & 1][mf], breg[kt & 1][nf], acc[mf][nf], 0, 0, 0);
        // distance-2 B prefetch into the buffer just consumed
        if (kt < 14) {
            #pragma unroll
            for (int nf = 0; nf < 4; ++nf)
                breg[kt & 1][nf] = *reinterpret_cast<const bf16x8*>(
                    bbase + (size_t)(kt + 2) * 16384 + nf * 128);
        }
    }

    // ================= epilogue: fast_gelu(acc+b1)*w2, reduce 512 cols =========
    float pr[12];
    #pragma unroll
    for (int i = 0; i < 12; ++i) pr[i] = 0.f;
    #pragma unroll
    for (int nf = 0; nf < 4; ++nf) {
        const int cg    = wv * 64 + nf * 16 + l15;
        const float b1v = b1[cg];
        const float w2v = w2[cg];
        #pragma unroll
        for (int mf = 0; mf < 3; ++mf) {
            #pragma unroll
            for (int rr = 0; rr < 4; ++rr) {
                const float ge = fast_gelu(acc[mf][nf][rr] + b1v);
                pr[mf * 4 + rr] = fmaf(ge, w2v, pr[mf * 4 + rr]);
            }
        }
    }
    #pragma unroll
    for (int i = 0; i < 12; ++i) {
        float v = pr[i];
        v += __shfl_xor(v, 1);
        v += __shfl_xor(v, 2);
        v += __shfl_xor(v, 4);
        v += __shfl_xor(v, 8);
        pr[i] = v;
    }
    if (l15 == 0) {
        #pragma unroll
        for (int mf = 0; mf < 3; ++mf)
            #pragma unroll
            for (int rr = 0; rr < 4; ++rr)
                gp[wv][mf * 16 + l4 * 4 + rr] = pr[mf * 4 + rr];
    }
    __syncthreads();
    if (tid < BM) {
        const int grow = brow + tid;
        if (grow < N_NODES) {
            float s = b2[0];
            #pragma unroll
            for (int w = 0; w < 8; ++w) s += gp[w][tid];
            gate[grow] = s;
        }
    }
}

// ---- Kernel 2: segment softmax + weighted pool ------------------------------
__global__ void __launch_bounds__(256) k_pool(const float* __restrict__ h,
                                              const int* __restrict__ bv,
                                              const float* __restrict__ gate,
                                              float* __restrict__ out) {
    const int g   = blockIdx.x;
    const int tid = threadIdx.x;
    __shared__ int   s_bounds[2];
    __shared__ float s_red[4];
    __shared__ float s_alpha[256];

    if (tid == 0) {
        int lo = 0, hi = N_NODES;
        while (lo < hi) { int mid = (lo + hi) >> 1; if (bv[mid] < g) lo = mid + 1; else hi = mid; }
        s_bounds[0] = lo;
        int lo2 = lo, hi2 = N_NODES;
        while (lo2 < hi2) { int mid = (lo2 + hi2) >> 1; if (bv[mid] < g + 1) lo2 = mid + 1; else hi2 = mid; }
        s_bounds[1] = lo2;
    }
    __syncthreads();
    const int start = s_bounds[0], end = s_bounds[1];

    float2 acc = make_float2(0.f, 0.f);
    if (start < end) {
        const int lane = tid & 63, wv = tid >> 6;
        float lm = -FLT_MAX;
        for (int i = start + tid; i < end; i += 256) lm = fmaxf(lm, gate[i]);
        #pragma unroll
        for (int o = 32; o; o >>= 1) lm = fmaxf(lm, __shfl_xor(lm, o));
        if (lane == 0) s_red[wv] = lm;
        __syncthreads();
        const float m = fmaxf(fmaxf(s_red[0], s_red[1]), fmaxf(s_red[2], s_red[3]));
        __syncthreads();
        float ls = 0.f;
        for (int i = start + tid; i < end; i += 256) ls += expf(gate[i] - m);
        #pragma unroll
        for (int o = 32; o; o >>= 1) ls += __shfl_xor(ls, o);
        if (lane == 0) s_red[wv] = ls;
        __syncthreads();
        const float inv = 1.f / (s_red[0] + s_red[1] + s_red[2] + s_red[3]);
        const float* hcol = h + tid * 2;
        for (int base = start; base < end; base += 256) {
            const int j = base + tid;
            const float av = (j < end) ? expf(gate[j] - m) * inv : 0.f;
            __syncthreads();
            s_alpha[tid] = av;
            __syncthreads();
            const int cnt = min(256, end - base);
            for (int jj = 0; jj < cnt; ++jj) {
                const float a = s_alpha[jj];
                const float2 hv = *reinterpret_cast<const float2*>(
                    hcol + (size_t)(base + jj) * HID);
                acc.x = fmaf(a, hv.x, acc.x);
                acc.y = fmaf(a, hv.y, acc.y);
            }
        }
    }
    *reinterpret_cast<float2*>(out + (size_t)g * HID + tid * 2) = acc;
}

// ---- launcher ---------------------------------------------------------------
extern "C" void kernel_launch(void* const* d_in, const int* in_sizes, int n_in,
                              void* d_out, int out_size, void* d_ws, size_t ws_size,
                              hipStream_t stream) {
    const float* h  = (const float*)d_in[0];
    const int*   bv = (const int*)d_in[1];
    const float* W1 = (const float*)d_in[2];
    const float* b1 = (const float*)d_in[3];
    const float* W2 = (const float*)d_in[4];
    const float* b2 = (const float*)d_in[5];
    float* out = (float*)d_out;

    char* ws = (char*)d_ws;
    bf16_t* bt   = (bf16_t*)ws;                    // tiled B: 512*512*2 = 524288 B
    float*  gate = (float*)(ws + 524288);          // 100000*4 B

    k_w1t_tiled<<<dim3(128), dim3(256), 0, stream>>>(W1, bt);
    k_gemm_gate<<<dim3(NBLK), dim3(512), 0, stream>>>(h, bt, b1, W2, b2, gate);
    k_pool<<<dim3(NGRAPH), dim3(256), 0, stream>>>(h, bv, gate, out);
}